// Round 10
// baseline (67.243 us; speedup 1.0000x reference)
//
#include <hip/hip_runtime.h>
#include <hip/hip_bf16.h>

// B=4, T=4096, E=512, H=64. out fp32 [B,T,H].
#define Bn 4
#define Tn 4096
#define En 512
#define Hn 64
#define NEGINF -3e38f
// 0.125 (1/sqrt(64)) * log2(e): QK^T output lands in log2 domain
#define QSCALE 0.1803368801f

typedef __attribute__((ext_vector_type(8))) __bf16 bf16x8;
typedef __attribute__((ext_vector_type(4))) __bf16 bf16x4;
typedef __attribute__((ext_vector_type(4))) float f32x4;

#define MFMA16(a, b, c) __builtin_amdgcn_mfma_f32_16x16x32_bf16(a, b, c, 0, 0, 0)

__device__ __forceinline__ unsigned short f2bf(float f) {
    union { float f; unsigned u; } v; v.f = f;
    unsigned r = v.u + 0x7fffu + ((v.u >> 16) & 1u);
    return (unsigned short)(r >> 16);
}
__device__ __forceinline__ unsigned cvtpk(float a, float b) {
    unsigned d;
    asm("v_cvt_pk_bf16_f32 %0, %1, %2" : "=v"(d) : "v"(a), "v"(b));
    return d;
}
__device__ __forceinline__ float exp2fast(float x) {
    float r;
    asm("v_exp_f32 %0, %1" : "=v"(r) : "v"(x));
    return r;
}

// ---------------- kernel 1: W fp32 -> bf16 concat [192][512] ----------------
__global__ void wcvt(const float* __restrict__ Wq, const float* __restrict__ Wk,
                     const float* __restrict__ Wv, unsigned short* __restrict__ Wo) {
    int i = blockIdx.x * 256 + threadIdx.x;      // 0..98303
    int mat = i >> 15;                            // each W is 64*512 = 32768
    int off = i & 32767;
    const float* s = (mat == 0) ? Wq : ((mat == 1) ? Wk : Wv);
    Wo[i] = f2bf(s[off]);
}

// ---------------- kernel 2: fused QKV projection (bf16 MFMA GEMM) -----------
// q16 is pre-scaled by QSCALE so attn's QK^T lands in log2 domain.
__launch_bounds__(256, 2)
__global__ void proj(const float* __restrict__ x, const unsigned short* __restrict__ Wo,
                     unsigned short* __restrict__ q16, unsigned short* __restrict__ k16,
                     unsigned short* __restrict__ vt16) {
    __shared__ unsigned short sA[64 * 72];
    __shared__ unsigned short sW[192 * 72];
    const int tid = threadIdx.x;
    const int w = tid >> 6, lane = tid & 63, r = lane & 15, g = lane >> 4;
    const int row0 = blockIdx.x * 64;

    f32x4 acc[12];
#pragma unroll
    for (int i = 0; i < 12; ++i) acc[i] = (f32x4){0.f, 0.f, 0.f, 0.f};

    for (int k0 = 0; k0 < En; k0 += 64) {
#pragma unroll
        for (int i = 0; i < 2; ++i) {
            int c = tid + i * 256; int arow = c >> 3, kc = (c & 7) * 8;
            const float4* xp = (const float4*)&x[(row0 + arow) * En + k0 + kc];
            float4 f0 = xp[0], f1 = xp[1];
            union { bf16x8 v; unsigned u32[4]; } t;
            t.u32[0] = cvtpk(f0.x, f0.y); t.u32[1] = cvtpk(f0.z, f0.w);
            t.u32[2] = cvtpk(f1.x, f1.y); t.u32[3] = cvtpk(f1.z, f1.w);
            *(bf16x8*)&sA[arow * 72 + kc] = t.v;
        }
#pragma unroll
        for (int i = 0; i < 6; ++i) {
            int c = tid + i * 256; int wrow = c >> 3, kc = (c & 7) * 8;
            bf16x8 wv = *(const bf16x8*)&Wo[wrow * En + k0 + kc];
            *(bf16x8*)&sW[wrow * 72 + kc] = wv;
        }
        __syncthreads();
        bf16x8 a0 = *(bf16x8*)&sA[(w * 16 + r) * 72 + g * 8];
        bf16x8 a1 = *(bf16x8*)&sA[(w * 16 + r) * 72 + 32 + g * 8];
#pragma unroll
        for (int ct = 0; ct < 12; ++ct) {
            bf16x8 b0 = *(bf16x8*)&sW[(ct * 16 + r) * 72 + g * 8];
            bf16x8 b1 = *(bf16x8*)&sW[(ct * 16 + r) * 72 + 32 + g * 8];
            acc[ct] = MFMA16(a0, b0, acc[ct]);
            acc[ct] = MFMA16(a1, b1, acc[ct]);
        }
        __syncthreads();
    }
#pragma unroll
    for (int ct = 0; ct < 12; ++ct) {
        int n = ct * 16 + r;
#pragma unroll
        for (int reg = 0; reg < 4; ++reg) {
            int gr = row0 + w * 16 + g * 4 + reg;
            if (n < 64) {
                q16[gr * 64 + n] = f2bf(acc[ct][reg] * QSCALE);
            } else if (n < 128) {
                k16[gr * 64 + (n - 64)] = f2bf(acc[ct][reg]);
            } else {
                int h = n - 128; int bb = gr >> 12; int t = gr & 4095;
                vt16[((bb * 64 + h) << 12) + t] = f2bf(acc[ct][reg]);
            }
        }
    }
}

// ---------------- kernel 3: causal flash attention (fat tile, 8-way sk) ------
// 256 blocks x 512 thr (8 waves). Block = one 64-row q-tile, 1 block/CU,
// b = bid&3 -> one batch per XCD. KV tile 256/iter, DOUBLE-buffer
// 2 x (K 32KB | V 32KB) = 128KB, 1 barrier/iter, T14 early-issue staging.
// Each wave: ALL 64 q-rows (4 qf) x its own 32-kv window (sk) -> K/V LDS
// read exactly once per iter. 8-way merge via oM (128KB) overlaid post-loop.
// Softmax in log2 domain; P packed via v_cvt_pk_bf16_f32; defer-max THR=8.
__launch_bounds__(512, 2)
__global__ void attn(const unsigned short* __restrict__ q16, const unsigned short* __restrict__ k16,
                     const unsigned short* __restrict__ vt16, float* __restrict__ out) {
    __shared__ __align__(16) unsigned char lds[2][65536];  // [buf][K 32KB | V 32KB]
    __shared__ float mM[8][64], lM[8][64];
    float* const oMp = (float*)&lds[0][0];                 // overlay [8][64][64] f32 = 128KB

    const int tid = threadIdx.x;
    const int sk = tid >> 6, lane = tid & 63, r = lane & 15, g = lane >> 4;
    const int bid = blockIdx.x;
    const int b = bid & 3;                                 // one batch per XCD
    const int jt = 63 - (bid >> 2);
    const size_t kbase = (size_t)b * Tn;

    const int q0 = jt * 64;
    const int nIt = (jt + 4) >> 2;                         // ceil(64(jt+1)/256)

    // Q B-frags: 4 qf groups of 16 q-rows
    bf16x8 bq[4][2];
#pragma unroll
    for (int qf = 0; qf < 4; ++qf) {
        const unsigned short* qp = &q16[(kbase + q0 + qf * 16 + r) * 64 + g * 8];
        bq[qf][0] = *(const bf16x8*)qp;
        bq[qf][1] = *(const bf16x8*)(qp + 32);
    }

    f32x4 o[4][4];
#pragma unroll
    for (int qf = 0; qf < 4; ++qf)
#pragma unroll
        for (int i = 0; i < 4; ++i) o[qf][i] = (f32x4){0.f, 0.f, 0.f, 0.f};
    float m_[4] = {-1e30f, -1e30f, -1e30f, -1e30f}, l_[4] = {0.f, 0.f, 0.f, 0.f};

    // prologue: stage kv tile 0 into buf 0 (128B/thread)
    {
        int row = tid >> 2, cb = (tid & 3) * 32;
#pragma unroll
        for (int p = 0; p < 2; ++p) {
            int rr = p * 128 + row, sw = (rr & 7) << 4;
            const char* src = (const char*)k16 + (kbase + rr) * 128 + cb;
            *(bf16x8*)&lds[0][rr * 128 + (cb ^ sw)] = *(const bf16x8*)src;
            *(bf16x8*)&lds[0][rr * 128 + ((cb + 16) ^ sw)] = *(const bf16x8*)(src + 16);
        }
        int cv = (tid & 15) * 32;
#pragma unroll
        for (int p = 0; p < 2; ++p) {
            int h = p * 32 + (tid >> 4), sw = (h & 7) << 4;
            const char* src = (const char*)vt16 + ((size_t)(b * 64 + h)) * 8192 + cv;
            *(bf16x8*)&lds[0][32768 + h * 512 + (cv ^ sw)] = *(const bf16x8*)src;
            *(bf16x8*)&lds[0][32768 + h * 512 + ((cv + 16) ^ sw)] = *(const bf16x8*)(src + 16);
        }
    }
    __syncthreads();

    for (int it = 0; it < nIt; ++it) {
        const int pp = it & 1;
        const int kv0 = it * 256;
        const bool more = (it + 1 < nIt);
        // T14: issue next-tile global loads early
        bf16x8 st[8];
        int sd[8];
        if (more) {
            int nkv = kv0 + 256;
            int row = tid >> 2, cb = (tid & 3) * 32;
#pragma unroll
            for (int p = 0; p < 2; ++p) {
                int rr = p * 128 + row, sw = (rr & 7) << 4;
                const char* src = (const char*)k16 + (kbase + nkv + rr) * 128 + cb;
                st[p * 2] = *(const bf16x8*)src;
                st[p * 2 + 1] = *(const bf16x8*)(src + 16);
                sd[p * 2] = rr * 128 + (cb ^ sw);
                sd[p * 2 + 1] = rr * 128 + ((cb + 16) ^ sw);
            }
            int cv = (tid & 15) * 32;
#pragma unroll
            for (int p = 0; p < 2; ++p) {
                int h = p * 32 + (tid >> 4), sw = (h & 7) << 4;
                const char* src = (const char*)vt16 + ((size_t)(b * 64 + h)) * 8192 + (size_t)nkv * 2 + cv;
                st[4 + p * 2] = *(const bf16x8*)src;
                st[4 + p * 2 + 1] = *(const bf16x8*)(src + 16);
                sd[4 + p * 2] = 32768 + h * 512 + (cv ^ sw);
                sd[4 + p * 2 + 1] = 32768 + h * 512 + ((cv + 16) ^ sw);
            }
        }
        const int kv_w = kv0 + sk * 32;                   // this wave's window
        if (kv_w <= q0 + 63) {                            // wave-uniform causal skip
            const unsigned char* K = &lds[pp][0];
            const unsigned char* V = &lds[pp][32768];
            f32x4 s[4][2];
            __builtin_amdgcn_s_setprio(1);
#pragma unroll
            for (int ct = 0; ct < 2; ++ct) {
                int row = sk * 32 + ct * 16 + r;
                int base = row * 128, sw = (row & 7) << 4;
                bf16x8 ak0 = *(const bf16x8*)&K[base + ((g * 16) ^ sw)];
                bf16x8 ak1 = *(const bf16x8*)&K[base + ((64 + g * 16) ^ sw)];
#pragma unroll
                for (int qf = 0; qf < 4; ++qf) {
                    f32x4 t = (f32x4){0.f, 0.f, 0.f, 0.f};
                    t = MFMA16(ak0, bq[qf][0], t);
                    t = MFMA16(ak1, bq[qf][1], t);
                    s[qf][ct] = t;
                }
            }
            __builtin_amdgcn_s_setprio(0);
            // diagonal masking (log2 domain: no scale mul needed)
            if (kv_w + 31 > q0) {
#pragma unroll
                for (int qf = 0; qf < 4; ++qf) {
                    int qq = q0 + qf * 16 + r;
#pragma unroll
                    for (int ct = 0; ct < 2; ++ct)
#pragma unroll
                        for (int reg = 0; reg < 4; ++reg) {
                            int kv = kv_w + ct * 16 + g * 4 + reg;
                            if (kv > qq) s[qf][ct][reg] = NEGINF;
                        }
                }
            }
            // per-qf window max (7-op tree + 2 shuffles)
            float mx[4];
#pragma unroll
            for (int qf = 0; qf < 4; ++qf) {
                float a0 = fmaxf(fmaxf(s[qf][0][0], s[qf][0][1]), fmaxf(s[qf][0][2], s[qf][0][3]));
                float a1 = fmaxf(fmaxf(s[qf][1][0], s[qf][1][1]), fmaxf(s[qf][1][2], s[qf][1][3]));
                float v = fmaxf(a0, a1);
                v = fmaxf(v, __shfl_xor(v, 16));
                v = fmaxf(v, __shfl_xor(v, 32));
                mx[qf] = v;
            }
            bool need = (mx[0] > m_[0] + 8.0f) || (mx[1] > m_[1] + 8.0f) ||
                        (mx[2] > m_[2] + 8.0f) || (mx[3] > m_[3] + 8.0f);
            if (__any(need)) {
#pragma unroll
                for (int qf = 0; qf < 4; ++qf) {
                    float mn = fmaxf(m_[qf], mx[qf]);
                    float corr = exp2fast(m_[qf] - mn);
                    m_[qf] = mn;
                    l_[qf] *= corr;
                    float cq[4];
#pragma unroll
                    for (int reg = 0; reg < 4; ++reg) cq[reg] = __shfl(corr, g * 4 + reg);
#pragma unroll
                    for (int cth = 0; cth < 4; ++cth)
#pragma unroll
                        for (int reg = 0; reg < 4; ++reg) o[qf][cth][reg] *= cq[reg];
                }
            }
            union { bf16x8 v; unsigned u32[4]; } pk[4];
#pragma unroll
            for (int qf = 0; qf < 4; ++qf) {
#pragma unroll
                for (int ct = 0; ct < 2; ++ct)
#pragma unroll
                    for (int reg = 0; reg < 4; ++reg)
                        s[qf][ct][reg] = exp2fast(s[qf][ct][reg] - m_[qf]);
                float sm = ((s[qf][0][0] + s[qf][0][1]) + (s[qf][0][2] + s[qf][0][3])) +
                           ((s[qf][1][0] + s[qf][1][1]) + (s[qf][1][2] + s[qf][1][3]));
                sm += __shfl_xor(sm, 16);
                sm += __shfl_xor(sm, 32);
                l_[qf] += sm;
                pk[qf].u32[0] = cvtpk(s[qf][0][0], s[qf][0][1]);
                pk[qf].u32[1] = cvtpk(s[qf][0][2], s[qf][0][3]);
                pk[qf].u32[2] = cvtpk(s[qf][1][0], s[qf][1][1]);
                pk[qf].u32[3] = cvtpk(s[qf][1][2], s[qf][1][3]);
            }
            // PV: V B-frag (32-kv window = one k=32 MFMA per cth), shared by 4 qf
            __builtin_amdgcn_s_setprio(1);
#pragma unroll
            for (int cth = 0; cth < 4; ++cth) {
                int h = cth * 16 + r;
                int vb = h * 512, sw2 = (h & 7) << 4;
                int off = sk * 64 + g * 8;
                union { bf16x8 v; bf16x4 h4[2]; } vv;
                vv.h4[0] = *(const bf16x4*)&V[vb + (off ^ sw2)];
                vv.h4[1] = *(const bf16x4*)&V[vb + ((off + 32) ^ sw2)];
#pragma unroll
                for (int qf = 0; qf < 4; ++qf)
                    o[qf][cth] = MFMA16(pk[qf].v, vv.v, o[qf][cth]);
            }
            __builtin_amdgcn_s_setprio(0);
        }
        if (more) {
            unsigned char* D = &lds[pp ^ 1][0];
#pragma unroll
            for (int p = 0; p < 8; ++p) *(bf16x8*)&D[sd[p]] = st[p];
        }
        __syncthreads();
    }

    // ---- partials to LDS (oM overlays the double-buffer; loop done) ----
#pragma unroll
    for (int qf = 0; qf < 4; ++qf)
#pragma unroll
        for (int cth = 0; cth < 4; ++cth)
#pragma unroll
            for (int reg = 0; reg < 4; ++reg)
                oMp[(sk * 64 + qf * 16 + g * 4 + reg) * 64 + cth * 16 + r] = o[qf][cth][reg];
    if (lane < 16) {
#pragma unroll
        for (int qf = 0; qf < 4; ++qf) {
            mM[sk][qf * 16 + lane] = m_[qf];
            lM[sk][qf * 16 + lane] = l_[qf];
        }
    }
    __syncthreads();

    // ---- 8-way merge: thread t -> row t>>3, cols (t&7)*8..+8 ----
    {
        int row = tid >> 3, c0 = (tid & 7) * 8;
        float m8[8];
#pragma unroll
        for (int i = 0; i < 8; ++i) m8[i] = mM[i][row];
        float M = fmaxf(fmaxf(fmaxf(m8[0], m8[1]), fmaxf(m8[2], m8[3])),
                        fmaxf(fmaxf(m8[4], m8[5]), fmaxf(m8[6], m8[7])));
        float wt[8], L = 0.f;
#pragma unroll
        for (int i = 0; i < 8; ++i) {
            wt[i] = exp2fast(m8[i] - M);
            L += wt[i] * lM[i][row];
        }
        float inv = 1.0f / L;
        float acc[8];
#pragma unroll
        for (int jj = 0; jj < 8; ++jj) acc[jj] = 0.f;
#pragma unroll
        for (int i = 0; i < 8; ++i) {
            const float* src = &oMp[(i * 64 + row) * 64 + c0];
            f32x4 v0 = *(const f32x4*)src;
            f32x4 v1 = *(const f32x4*)(src + 4);
#pragma unroll
            for (int jj = 0; jj < 4; ++jj) {
                acc[jj] += wt[i] * v0[jj];
                acc[4 + jj] += wt[i] * v1[jj];
            }
        }
        float4* op = (float4*)&out[(kbase + q0 + row) * 64 + c0];
        op[0] = (float4){acc[0] * inv, acc[1] * inv, acc[2] * inv, acc[3] * inv};
        op[1] = (float4){acc[4] * inv, acc[5] * inv, acc[6] * inv, acc[7] * inv};
    }
}

extern "C" void kernel_launch(void* const* d_in, const int* in_sizes, int n_in,
                              void* d_out, int out_size, void* d_ws, size_t ws_size,
                              hipStream_t stream) {
    const float* x  = (const float*)d_in[0];
    const float* Wq = (const float*)d_in[1];
    const float* Wk = (const float*)d_in[2];
    const float* Wv = (const float*)d_in[3];
    float* out = (float*)d_out;
    char* ws = (char*)d_ws;

    unsigned short* Wo  = (unsigned short*)ws;                       // 192*512*2   = 196608 B
    unsigned short* q16 = (unsigned short*)(ws + 196608);            // 16384*64*2  = 2 MiB
    unsigned short* k16 = (unsigned short*)(ws + 196608 + 2097152);
    unsigned short* v16 = (unsigned short*)(ws + 196608 + 2 * 2097152);

    hipLaunchKernelGGL(wcvt, dim3(384), dim3(256), 0, stream, Wq, Wk, Wv, Wo);
    hipLaunchKernelGGL(proj, dim3(256), dim3(256), 0, stream, x, Wo, q16, k16, v16);
    hipLaunchKernelGGL(attn, dim3(256), dim3(512), 0, stream, q16, k16, v16, out);
}